// Round 8
// baseline (196.757 us; speedup 1.0000x reference)
//
#include <hip/hip_runtime.h>
#include <cstdint>
#include <cstddef>

#define S_LEN   2048
#define D_MODEL 1024
#define N_HEADS 16
#define HEAD_DIM 64
#define BATCH   4
#define M_ROWS  (BATCH * S_LEN)   // 8192

typedef _Float16 half8  __attribute__((ext_vector_type(8)));
typedef _Float16 half4v __attribute__((ext_vector_type(4)));
typedef float    float4v __attribute__((ext_vector_type(4)));

#define AS1 __attribute__((address_space(1)))
#define AS3 __attribute__((address_space(3)))

#define QSCL 0.1803368801111832f   // (1/sqrt(64)) * log2(e), folded into Q proj

// byte-offset swizzle for 128-B LDS rows (8 x 16-B blocks per row) [attention K/V]
__device__ __forceinline__ int swz(int row, int byteInRow) {
    return row * 128 + ((((byteInRow >> 4) ^ (row & 7)) << 4)) + (byteInRow & 15);
}

// V key-permutation within 64-blocks (PV A-operand alignment with S^T C-frag)
__device__ __forceinline__ int vperm(int a) {
    return (a & 0x20) | ((a & 0x0C) << 1) | ((a & 0x10) >> 2) | (a & 3);
}

// ---------------------------------------------------------------- fused convert
__global__ __launch_bounds__(256) void cvt_all(const float* __restrict__ x,
                                               const float* __restrict__ wq,
                                               const float* __restrict__ wk,
                                               const float* __restrict__ wv,
                                               const float* __restrict__ wo,
                                               _Float16* __restrict__ dst) {
    const int NX = M_ROWS * D_MODEL / 4;
    const int NW = D_MODEL * D_MODEL / 4;
    int i = blockIdx.x * 256 + threadIdx.x;
    int j = i;
    const float4v* src;
    if (j < NX) src = (const float4v*)x;
    else {
        j -= NX;
        if (j < NW) src = (const float4v*)wq;
        else { j -= NW;
            if (j < NW) src = (const float4v*)wk;
            else { j -= NW;
                if (j < NW) src = (const float4v*)wv;
                else { j -= NW; src = (const float4v*)wo; }
            }
        }
    }
    float4v v = src[j];
    half4v h;
    h[0] = (_Float16)v[0]; h[1] = (_Float16)v[1];
    h[2] = (_Float16)v[2]; h[3] = (_Float16)v[3];
    ((half4v*)dst)[i] = h;
}

// ---------------------------------------------------------------- 8-phase GEMM
// C = A * B^T, K fixed at 1024. Tile 256x256, BK=64, 512 thr = 8 waves (2M x 4N),
// per-wave output 128x64 (acc[8][4]). LDS 2 x 64 KB buffers:
//   A: [mh(2)][wm(2)][64 rows][128 B]   B: [nh(2)][wn(4)][32 rows][128 B]
// Phase = C-quadrant (mh, nh): 12 ds_read_b128 + 1 half-tile stage (2 gloads)
// + barrier + lgkmcnt(0) + 16 MFMA + barrier. Half-tile death: A-mh0 after P1,
// B-nh0 after P2, A-mh1/B-nh1 after P3 -> stage schedule P0:Amh1(kt+1),
// P1:Bnh1(kt+1), P2:Amh0(kt+2), P3:Bnh0(kt+2). Ledger-counted waits:
// vmcnt(6) after P0 (need Bnh1(kt); 3 half-tiles issued after), vmcnt(8)
// after P3 (need Amh0/Bnh0(kt+1); 4 after). Tails compile-time adjusted.
// 16-B-granule XOR swizzle (g ^ row&7), pre-swizzled source, swizzled reads.
// MODE 0: fused QKV (N=3072): proj0=Q(xQSCL), proj1=K in [b,h,s,hd];
//         proj2=V transposed into Vt [b,h,hd,s'] vperm order.
// MODE 2: f32 out row-major + bias.
#define GK    1024
#define GNT   16
#define GBUF  65536
#define G2LDS 131072

#define VMC(N) asm volatile("s_waitcnt vmcnt(" #N ")" ::: "memory")

#define GPHASE(MH, NH, STAGE)                                                     \
    {                                                                             \
        half8 af[4][2], bf[2][2];                                                 \
        _Pragma("unroll")                                                         \
        for (int mi = 0; mi < 4; ++mi) {                                          \
            af[mi][0] = *(const half8*)(Ab + (MH)*16384 + aWOff + mi*2048 + swzk0);\
            af[mi][1] = *(const half8*)(Ab + (MH)*16384 + aWOff + mi*2048 + swzk1);\
        }                                                                         \
        _Pragma("unroll")                                                         \
        for (int ni = 0; ni < 2; ++ni) {                                          \
            bf[ni][0] = *(const half8*)(Ab + (NH)*16384 + bWOff + ni*2048 + swzk0);\
            bf[ni][1] = *(const half8*)(Ab + (NH)*16384 + bWOff + ni*2048 + swzk1);\
        }                                                                         \
        STAGE;                                                                    \
        __builtin_amdgcn_s_barrier();                                             \
        asm volatile("s_waitcnt lgkmcnt(0)" ::: "memory");                        \
        __builtin_amdgcn_sched_barrier(0);                                        \
        __builtin_amdgcn_s_setprio(1);                                            \
        _Pragma("unroll")                                                         \
        for (int mi = 0; mi < 4; ++mi)                                            \
            _Pragma("unroll")                                                     \
            for (int ni = 0; ni < 2; ++ni) {                                      \
                acc[(MH)*4+mi][(NH)*2+ni] = __builtin_amdgcn_mfma_f32_16x16x32_f16(\
                    af[mi][0], bf[ni][0], acc[(MH)*4+mi][(NH)*2+ni], 0, 0, 0);    \
                acc[(MH)*4+mi][(NH)*2+ni] = __builtin_amdgcn_mfma_f32_16x16x32_f16(\
                    af[mi][1], bf[ni][1], acc[(MH)*4+mi][(NH)*2+ni], 0, 0, 0);    \
            }                                                                     \
        __builtin_amdgcn_s_setprio(0);                                            \
    }

#define GKTILE(KT, S0, S1, S2, S3, W0, W3)                                        \
    {                                                                             \
        const char* Ab = smem + ((KT) & 1) * GBUF;                                \
        GPHASE(0, 0, S0); W0; __builtin_amdgcn_s_barrier();                       \
        GPHASE(0, 1, S1);     __builtin_amdgcn_s_barrier();                       \
        GPHASE(1, 0, S2);     __builtin_amdgcn_s_barrier();                       \
        GPHASE(1, 1, S3); W3; __builtin_amdgcn_s_barrier();                       \
    }

template <int MODE>
__global__ __launch_bounds__(512, 2) void gemm256(const _Float16* __restrict__ A,
                                                  const _Float16* __restrict__ Bw,
                                                  _Float16* __restrict__ O1,
                                                  _Float16* __restrict__ O2,
                                                  _Float16* __restrict__ O3,
                                                  float* __restrict__ Of,
                                                  const float* __restrict__ bias,
                                                  int N) {
    extern __shared__ char smem[];

    const int tid  = threadIdx.x;
    const int wave = tid >> 6;
    const int lane = tid & 63;
    const int quad = lane >> 4;
    const int l16  = lane & 15;
    const int wm   = wave >> 2;        // 0..1 (M strip of 128)
    const int wn   = wave & 3;         // 0..3 (N strip of 64)

    const int rowBase = blockIdx.x * 256;
    const int colBase = blockIdx.y * 256;

    // staging: linear LDS dest (tid*16 within 8 KB gload), pre-swizzled source.
    const int r   = tid >> 3;                         // 0..63 local row
    const int csw = ((tid & 7) ^ (r & 7)) * 8;        // swizzled K-granule
    const _Float16* aBase = A  + (size_t)(rowBase + r) * GK + csw;
    const _Float16* bBase = Bw + (size_t)(colBase + (r >> 5) * 64 + (r & 31)) * GK + csw;
    const int dstOff = tid * 16;

    // A half-tile mh of K-tile kt: LDS rows mh*128+[0..127] = (wm0|wm1 x 64)
    auto stageA = [&](int kt, int mh) {
        char* dst = smem + (kt & 1) * GBUF + mh * 16384 + dstOff;
        const _Float16* src = aBase + (size_t)mh * 64 * GK + (size_t)kt * 64;
        __builtin_amdgcn_global_load_lds((const AS1 void*)src,
                                         (AS3 void*)dst, 16, 0, 0);
        __builtin_amdgcn_global_load_lds((const AS1 void*)(src + (size_t)128 * GK),
                                         (AS3 void*)(dst + 8192), 16, 0, 0);
    };
    // B half-tile nh: LDS rows (B region) nh*128+[0..127] = 4 x 32-col slices
    auto stageB = [&](int kt, int nh) {
        char* dst = smem + (kt & 1) * GBUF + 32768 + nh * 16384 + dstOff;
        const _Float16* src = bBase + (size_t)nh * 32 * GK + (size_t)kt * 64;
        __builtin_amdgcn_global_load_lds((const AS1 void*)src,
                                         (AS3 void*)dst, 16, 0, 0);
        __builtin_amdgcn_global_load_lds((const AS1 void*)(src + (size_t)128 * GK),
                                         (AS3 void*)(dst + 8192), 16, 0, 0);
    };

    const int swzk0 = ((quad)     ^ (l16 & 7)) << 4;
    const int swzk1 = ((quad + 4) ^ (l16 & 7)) << 4;
    const int aWOff = wm * 8192 + l16 * 128;
    const int bWOff = 32768 + wn * 4096 + l16 * 128;

    float4v acc[8][4] = {};

    // ---- prologue: 6 half-tiles (kt0 full + kt1 A-mh0,B-nh0); first 2 landed
    stageA(0, 0); stageB(0, 0); stageA(0, 1); stageB(0, 1); stageA(1, 0); stageB(1, 0);
    VMC(8);
    __builtin_amdgcn_s_barrier();

    // ---- main: kt pairs 0..13, all stages unconditional
    for (int ktp = 0; ktp < 7; ++ktp) {
        const int kt = 2 * ktp;
        GKTILE(kt,     stageA(kt + 1, 1), stageB(kt + 1, 1),
                       stageA(kt + 2, 0), stageB(kt + 2, 0), VMC(6), VMC(8));
        GKTILE(kt + 1, stageA(kt + 2, 1), stageB(kt + 2, 1),
                       stageA(kt + 3, 0), stageB(kt + 3, 0), VMC(6), VMC(8));
    }
    // ---- tail kt=14,15 (compile-time stage skips + adjusted waits)
    GKTILE(14, stageA(15, 1), stageB(15, 1), , , VMC(6), VMC(4));
    GKTILE(15, , , , , VMC(0), );

    // ---- epilogue: row = wm*128 + (mi>>2)*64 + (mi&3)*16 + quad*4 + i
    //                col = wn*64 + (ni>>1)*32 + (ni&1)*16 + l16
#pragma unroll
    for (int mi = 0; mi < 8; ++mi)
#pragma unroll
        for (int ni = 0; ni < 4; ++ni) {
            const int col = colBase + wn * 64 + (ni >> 1) * 32 + (ni & 1) * 16 + l16;
#pragma unroll
            for (int i = 0; i < 4; ++i) {
                const int row = rowBase + wm * 128 + (mi >> 2) * 64 + (mi & 3) * 16
                                + quad * 4 + i;
                float v = acc[mi][ni][i];
                if (MODE == 0) {
                    int b_ = row >> 11, s_ = row & 2047;
                    int proj = col >> 10, d = col & 1023;
                    int h_ = d >> 6, hd = d & 63;
                    if (proj == 2) {
                        int sp = (s_ & ~63) | vperm(s_ & 63);
                        O3[(((size_t)(b_ * 16 + h_) * 64 + hd) << 11) + sp] = (_Float16)v;
                    } else {
                        _Float16* dst = proj ? O2 : O1;
                        if (proj == 0) v *= QSCL;
                        dst[(((size_t)(b_ * 16 + h_) * 2048 + s_) << 6) + hd] = (_Float16)v;
                    }
                } else {
                    Of[(size_t)row * N + col] = v + bias[col];
                }
            }
        }
}

// ---------------------------------------------------------------- attention QK+softmax
// One 16-row side: QK^T from LDS K (XOR-swizzled), exp+mask, pack to f16 PV
// A-operand; l accumulated via ones-MFMA (row sums land in o-fragment layout).
template <bool MASKED>
__device__ __forceinline__ void qk_sm(const half8 qf[2],
                                      const _Float16* __restrict__ Ks,
                                      int krow0, int qt, int quad, int c,
                                      half8 (&pf)[2], float4v& ol, half8 ones) {
    float4v sT[4] = {};
    __builtin_amdgcn_s_setprio(1);
#pragma unroll
    for (int nt = 0; nt < 4; ++nt)
#pragma unroll
        for (int ks = 0; ks < 2; ++ks) {
            half8 kf = *(const half8*)((const char*)Ks + swz(nt * 16 + c, ks * 64 + quad * 16));
            sT[nt] = __builtin_amdgcn_mfma_f32_16x16x32_f16(kf, qf[ks], sT[nt], 0, 0, 0);
        }
    __builtin_amdgcn_s_setprio(0);

    const int qrow = qt + c;
#pragma unroll
    for (int kk = 0; kk < 2; ++kk) {
        float e[2][4];
#pragma unroll
        for (int jh = 0; jh < 2; ++jh) {
            const int nt = 2 * kk + jh;
#pragma unroll
            for (int i = 0; i < 4; ++i) {
                float ev = __builtin_amdgcn_exp2f(sT[nt][i]);
                if (MASKED)
                    ev = (krow0 + nt * 16 + quad * 4 + i <= qrow) ? ev : 0.0f;
                e[jh][i] = ev;
            }
        }
        auto p0 = __builtin_amdgcn_cvt_pkrtz(e[0][0], e[0][1]);
        auto p1 = __builtin_amdgcn_cvt_pkrtz(e[0][2], e[0][3]);
        auto p2 = __builtin_amdgcn_cvt_pkrtz(e[1][0], e[1][1]);
        auto p3 = __builtin_amdgcn_cvt_pkrtz(e[1][2], e[1][3]);
        half8 pfv;
        pfv[0] = p0[0]; pfv[1] = p0[1]; pfv[2] = p1[0]; pfv[3] = p1[1];
        pfv[4] = p2[0]; pfv[5] = p2[1]; pfv[6] = p3[0]; pfv[7] = p3[1];
        pf[kk] = pfv;
        ol = __builtin_amdgcn_mfma_f32_16x16x32_f16(pfv, ones, ol, 0, 0, 0);
    }
}

// ---------------------------------------------------------------- flash attention
// (attn_flash10, unchanged: best-measured structure; 4 waves x 16 rows/side,
// shared-V PV, ones-MFMA l-sum, per-CU balance remap.)
__global__ __launch_bounds__(256, 4) void attn_flash10(const _Float16* __restrict__ Q,
                                                       const _Float16* __restrict__ Kg,
                                                       const _Float16* __restrict__ Vt,
                                                       _Float16* __restrict__ Ctx) {
    __shared__ __align__(16) _Float16 Ks[2 * 64 * 64];  // 16 KB dbuf
    __shared__ __align__(16) _Float16 Vs[2 * 64 * 64];  // 16 KB dbuf

    const int tid  = threadIdx.x;
    const int wave = tid >> 6;
    const int lane = tid & 63;
    const int quad = lane >> 4;
    const int c    = lane & 15;

    const int h    = blockIdx.x;
    const int y    = blockIdx.y;
    const int bb   = blockIdx.z;
    const int hp   = (y < 8) ? y : 23 - y;   // per-CU balance remap (bijective)
    const int pair = hp >> 1;
    const int hf   = hp & 1;

    const int qA   = pair * 128 + hf * 64 + wave * 16;
    const int qB   = (15 - pair) * 128 + hf * 64 + wave * 16;
    const int nkbB = (15 - pair) * 2 + hf + 1;

    const _Float16* Qb  = Q  + ((size_t)(bb * 16 + h) << 17);
    const _Float16* Kb  = Kg + ((size_t)(bb * 16 + h) << 17);
    const _Float16* Vtb = Vt + ((size_t)(bb * 16 + h) << 17);

    half8 qfA[2], qfB[2];
    {
        const _Float16* qa = Qb + (size_t)(qA + c) * 64;
        qfA[0] = *(const half8*)(qa + quad * 8);
        qfA[1] = *(const half8*)(qa + 32 + quad * 8);
        const _Float16* qb = Qb + (size_t)(qB + c) * 64;
        qfB[0] = *(const half8*)(qb + quad * 8);
        qfB[1] = *(const half8*)(qb + 32 + quad * 8);
    }

    size_t koff[2], voff[2];
#pragma unroll
    for (int it = 0; it < 2; ++it) {
        int F = it * 4096 + tid * 16;
        int rr = F >> 7;
        int blk = (tid & 7) ^ (rr & 7);
        koff[it] = (size_t)rr * 64 + blk * 8;
        voff[it] = (size_t)rr * 2048 + blk * 8;
    }

    float4v oA[4] = {}, oB[4] = {};
    float4v olA = {}, olB = {};
    half8 ones;
#pragma unroll
    for (int i = 0; i < 8; ++i) ones[i] = (_Float16)1.0f;

    auto stage = [&](int kb, int buf) {
        const size_t kbase = (size_t)kb * 64 * 64;
#pragma unroll
        for (int it = 0; it < 2; ++it) {
            __builtin_amdgcn_global_load_lds(
                (const AS1 void*)(Kb + kbase + koff[it]),
                (AS3 void*)((char*)Ks + buf * 8192 + it * 4096 + wave * 1024), 16, 0, 0);
            __builtin_amdgcn_global_load_lds(
                (const AS1 void*)(Vtb + kb * 64 + voff[it]),
                (AS3 void*)((char*)Vs + buf * 8192 + it * 4096 + wave * 1024), 16, 0, 0);
        }
    };

    stage(0, 0);
    for (int kb = 0; kb < nkbB; ++kb) {
        __syncthreads();                       // buf kb ready; prev buf free
        if (kb + 1 < nkbB) stage(kb + 1, (kb + 1) & 1);

        const _Float16* Ksb = Ks + (kb & 1) * 4096;
        const _Float16* Vsb = Vs + (kb & 1) * 4096;
        const int krow0 = kb * 64;
        const bool aB = krow0 <= qB + 15;
        const bool aA = krow0 <= qA + 15;

        half8 pfB[2], pfA[2];
        if (aB) {
            if (krow0 + 63 <= qB)
                qk_sm<false>(qfB, Ksb, krow0, qB, quad, c, pfB, olB, ones);
            else
                qk_sm<true >(qfB, Ksb, krow0, qB, quad, c, pfB, olB, ones);
        }
        if (aA) {
            if (krow0 + 63 <= qA)
                qk_sm<false>(qfA, Ksb, krow0, qA, quad, c, pfA, olA, ones);
            else
                qk_sm<true >(qfA, Ksb, krow0, qA, quad, c, pfA, olA, ones);
        }

        // ---- PV: each vf read once, shared by both sides
        __builtin_amdgcn_s_setprio(1);
#pragma unroll
        for (int kk = 0; kk < 2; ++kk)
#pragma unroll
            for (int dt = 0; dt < 4; ++dt) {
                half8 vf = *(const half8*)((const char*)Vsb + swz(dt * 16 + c, kk * 64 + quad * 16));
                if (aB)
                    oB[dt] = __builtin_amdgcn_mfma_f32_16x16x32_f16(
                        pfB[kk], vf, oB[dt], 0, 0, 0);
                if (aA)
                    oA[dt] = __builtin_amdgcn_mfma_f32_16x16x32_f16(
                        pfA[kk], vf, oA[dt], 0, 0, 0);
            }
        __builtin_amdgcn_s_setprio(0);
    }

    // ---- normalize + write ctx [b, s, h*64+hd]; ol rows match o rows per lane
#pragma unroll
    for (int t = 0; t < 2; ++t) {
        const int qt = t ? qB : qA;
#pragma unroll
        for (int i = 0; i < 4; ++i) {
            const float lsum = t ? olB[i] : olA[i];
            const float inv = 1.0f / lsum;
            const int row_g = qt + quad * 4 + i;
            _Float16* dst = Ctx + (size_t)(bb * 2048 + row_g) * 1024 + h * 64;
#pragma unroll
            for (int dt = 0; dt < 4; ++dt) {
                const float ov = t ? oB[dt][i] : oA[dt][i];
                dst[dt * 16 + c] = (_Float16)(ov * inv);
            }
        }
    }
}

// ---------------------------------------------------------------- launch
extern "C" void kernel_launch(void* const* d_in, const int* in_sizes, int n_in,
                              void* d_out, int out_size, void* d_ws, size_t ws_size,
                              hipStream_t stream) {
    const float* x  = (const float*)d_in[0];
    const float* Wq = (const float*)d_in[1];
    const float* Wk = (const float*)d_in[2];
    const float* Wv = (const float*)d_in[3];
    const float* Wo = (const float*)d_in[4];
    const float* bo = (const float*)d_in[5];
    float* out = (float*)d_out;

    _Float16* Xh    = (_Float16*)d_ws;
    _Float16* Wqkvh = Xh + (size_t)M_ROWS * D_MODEL;     // Wq | Wk | Wv (contig)
    _Float16* Woh   = Wqkvh + (size_t)3 * D_MODEL * D_MODEL;
    _Float16* Qh    = Woh + (size_t)D_MODEL * D_MODEL;   // [b,h,s,hd], pre-scaled
    _Float16* Kh    = Qh + (size_t)M_ROWS * D_MODEL;     // [b,h,s,hd]
    _Float16* Vth   = Kh + (size_t)M_ROWS * D_MODEL;     // [b,h,hd,s'] vperm order
    _Float16* Ch    = Vth + (size_t)M_ROWS * D_MODEL;    // [b*s, d]

    static bool s_init = false;
    if (!s_init) {
        hipFuncSetAttribute((const void*)gemm256<0>,
                            hipFuncAttributeMaxDynamicSharedMemorySize, G2LDS);
        hipFuncSetAttribute((const void*)gemm256<2>,
                            hipFuncAttributeMaxDynamicSharedMemorySize, G2LDS);
        s_init = true;
    }

    const int TOT4 = (M_ROWS * D_MODEL + 4 * D_MODEL * D_MODEL) / 4;
    cvt_all<<<TOT4 / 256, 256, 0, stream>>>(x, Wq, Wk, Wv, Wo, Xh);

    // fused QKV projection: Xh (8192x1024) x [Wq|Wk|Wv]^T (3072x1024)
    gemm256<0><<<dim3(M_ROWS / 256, 3072 / 256), 512, G2LDS, stream>>>(
        Xh, Wqkvh, Qh, Kh, Vth, nullptr, nullptr, 3072);

    attn_flash10<<<dim3(N_HEADS, 16, BATCH), 256, 0, stream>>>(Qh, Kh, Vth, Ch);

    gemm256<2><<<dim3(M_ROWS / 256, D_MODEL / 256), 512, G2LDS, stream>>>(
        Ch, Woh, nullptr, nullptr, nullptr, out, bo, D_MODEL);
}

// Round 9
// 160.085 us; speedup vs baseline: 1.2291x; 1.2291x over previous
//
#include <hip/hip_runtime.h>
#include <cstdint>
#include <cstddef>

#define S_LEN   2048
#define D_MODEL 1024
#define N_HEADS 16
#define HEAD_DIM 64
#define BATCH   4
#define M_ROWS  (BATCH * S_LEN)   // 8192

typedef _Float16 half8  __attribute__((ext_vector_type(8)));
typedef _Float16 half4v __attribute__((ext_vector_type(4)));
typedef float    float4v __attribute__((ext_vector_type(4)));

#define AS1 __attribute__((address_space(1)))
#define AS3 __attribute__((address_space(3)))

#define QSCL 0.1803368801111832f   // (1/sqrt(64)) * log2(e), folded into Q proj

// byte-offset swizzle for 128-B LDS rows (8 x 16-B blocks per row) [attention K/V]
__device__ __forceinline__ int swz(int row, int byteInRow) {
    return row * 128 + ((((byteInRow >> 4) ^ (row & 7)) << 4)) + (byteInRow & 15);
}

// V key-permutation within 64-blocks (PV A-operand alignment with S^T C-frag)
__device__ __forceinline__ int vperm(int a) {
    return (a & 0x20) | ((a & 0x0C) << 1) | ((a & 0x10) >> 2) | (a & 3);
}

// ---------------------------------------------------------------- fused convert
__global__ __launch_bounds__(256) void cvt_all(const float* __restrict__ x,
                                               const float* __restrict__ wq,
                                               const float* __restrict__ wk,
                                               const float* __restrict__ wv,
                                               const float* __restrict__ wo,
                                               _Float16* __restrict__ dst) {
    const int NX = M_ROWS * D_MODEL / 4;
    const int NW = D_MODEL * D_MODEL / 4;
    int i = blockIdx.x * 256 + threadIdx.x;
    int j = i;
    const float4v* src;
    if (j < NX) src = (const float4v*)x;
    else {
        j -= NX;
        if (j < NW) src = (const float4v*)wq;
        else { j -= NW;
            if (j < NW) src = (const float4v*)wk;
            else { j -= NW;
                if (j < NW) src = (const float4v*)wv;
                else { j -= NW; src = (const float4v*)wo; }
            }
        }
    }
    float4v v = src[j];
    half4v h;
    h[0] = (_Float16)v[0]; h[1] = (_Float16)v[1];
    h[2] = (_Float16)v[2]; h[3] = (_Float16)v[3];
    ((half4v*)dst)[i] = h;
}

// ---------------------------------------------------------------- pipelined GEMM
// EXACT round-1 verified kernel (153.8us config; ~800 TF effective split).
// C = A * B^T, K fixed 1024. Tile 256x128, BK=64, 512 thr = 8 waves (4M x 2N),
// 3-deep LDS K-tile pipeline, counted s_waitcnt vmcnt(6), raw s_barrier,
// 16-B-granule XOR swizzle both-sides.
// MODE 0: f16 out -> Q (pre-scaled by QSCL) / K in [b,h,s,hd]
// MODE 1: f16 out -> Vt [b,h,hd,s'] with vperm key order within 64-blocks
// MODE 2: f32 out row-major + bias
#define GK   1024
#define GNT  16                 // GK / 64 K-tiles
#define BUFB 49152              // per-buffer bytes: A 32768 + B 16384
#define GEMM_LDS (3 * BUFB)     // 147456

template <int MODE>
__global__ __launch_bounds__(512, 2) void gemm8p(const _Float16* __restrict__ A,
                                                 const _Float16* __restrict__ Bw,
                                                 _Float16* __restrict__ O1,
                                                 _Float16* __restrict__ O2,
                                                 float* __restrict__ Of,
                                                 const float* __restrict__ bias,
                                                 int N) {
    extern __shared__ char smem[];

    const int tid  = threadIdx.x;
    const int wave = tid >> 6;
    const int lane = tid & 63;
    const int quad = lane >> 4;
    const int l16  = lane & 15;
    const int wm   = wave >> 1;        // 0..3 (M strip of 64)
    const int wn   = wave & 1;         // 0..1 (N strip of 64)

    const int rowBase = blockIdx.x * 256;
    const int colBase = blockIdx.y * 128;

    const int srow = tid >> 3;                        // 0..63
    const int csw  = ((tid & 7) ^ (srow & 7)) * 8;    // source element offset
    const _Float16* aS[4];
    const _Float16* bS[2];
#pragma unroll
    for (int i = 0; i < 4; ++i)
        aS[i] = A + (size_t)(rowBase + i * 64 + srow) * GK + csw;
#pragma unroll
    for (int j = 0; j < 2; ++j)
        bS[j] = Bw + (size_t)(colBase + j * 64 + srow) * GK + csw;
    const int dstOff = tid * 16;

    auto stage = [&](int kt, int part) {              // 3 loads per part
        char* base = smem + (kt % 3) * BUFB;
        const size_t ko = (size_t)kt * 64;
        if (part == 0) {
            __builtin_amdgcn_global_load_lds((const AS1 void*)(aS[0] + ko),
                (AS3 void*)(base + 0 * 8192 + dstOff), 16, 0, 0);
            __builtin_amdgcn_global_load_lds((const AS1 void*)(aS[1] + ko),
                (AS3 void*)(base + 1 * 8192 + dstOff), 16, 0, 0);
            __builtin_amdgcn_global_load_lds((const AS1 void*)(bS[0] + ko),
                (AS3 void*)(base + 32768 + dstOff), 16, 0, 0);
        } else {
            __builtin_amdgcn_global_load_lds((const AS1 void*)(aS[2] + ko),
                (AS3 void*)(base + 2 * 8192 + dstOff), 16, 0, 0);
            __builtin_amdgcn_global_load_lds((const AS1 void*)(aS[3] + ko),
                (AS3 void*)(base + 3 * 8192 + dstOff), 16, 0, 0);
            __builtin_amdgcn_global_load_lds((const AS1 void*)(bS[1] + ko),
                (AS3 void*)(base + 32768 + 8192 + dstOff), 16, 0, 0);
        }
    };

    const int aRow = (wm * 64 + l16) * 128;
    const int bRow = (wn * 64 + l16) * 128;
    int swzk[2];
    swzk[0] = ((quad)     ^ (l16 & 7)) << 4;
    swzk[1] = ((quad + 4) ^ (l16 & 7)) << 4;

    float4v acc[4][4] = {};

    stage(0, 0); stage(0, 1); stage(1, 0); stage(1, 1);
    asm volatile("s_waitcnt vmcnt(6)" ::: "memory");
    __builtin_amdgcn_s_barrier();

#pragma unroll
    for (int kt = 0; kt < GNT; ++kt) {
        const char* Ab = smem + (kt % 3) * BUFB;
        const char* Bb = Ab + 32768;
#pragma unroll
        for (int ks = 0; ks < 2; ++ks) {
            half8 af[4], bf[4];
#pragma unroll
            for (int mi = 0; mi < 4; ++mi)
                af[mi] = *(const half8*)(Ab + aRow + mi * 2048 + swzk[ks]);
#pragma unroll
            for (int ni = 0; ni < 4; ++ni)
                bf[ni] = *(const half8*)(Bb + bRow + ni * 2048 + swzk[ks]);
            if (kt + 2 < GNT) stage(kt + 2, ks);
            __builtin_amdgcn_s_barrier();
            asm volatile("s_waitcnt lgkmcnt(0)" ::: "memory");
            __builtin_amdgcn_sched_barrier(0);
            __builtin_amdgcn_s_setprio(1);
#pragma unroll
            for (int mi = 0; mi < 4; ++mi)
#pragma unroll
                for (int ni = 0; ni < 4; ++ni)
                    acc[mi][ni] = __builtin_amdgcn_mfma_f32_16x16x32_f16(
                        af[mi], bf[ni], acc[mi][ni], 0, 0, 0);
            __builtin_amdgcn_s_setprio(0);
            if (ks == 1) {
                if (kt + 2 < GNT) {
                    asm volatile("s_waitcnt vmcnt(6)" ::: "memory");  // kt+1 landed
                } else if (kt + 1 < GNT) {
                    asm volatile("s_waitcnt vmcnt(0)" ::: "memory");  // tail drain
                }
            }
            __builtin_amdgcn_s_barrier();
        }
    }

    const int rowOff = wm * 64;
    const int colOff = wn * 64;
#pragma unroll
    for (int mi = 0; mi < 4; ++mi)
#pragma unroll
        for (int ni = 0; ni < 4; ++ni) {
            const int col = colBase + colOff + ni * 16 + l16;
#pragma unroll
            for (int i = 0; i < 4; ++i) {
                const int row = rowBase + rowOff + mi * 16 + quad * 4 + i;
                float v = acc[mi][ni][i];
                if (MODE == 0) {
                    int b_ = row >> 11, s_ = row & 2047;
                    int proj = col >> 10, d = col & 1023;
                    int h_ = d >> 6, hd = d & 63;
                    _Float16* dst = proj ? O2 : O1;
                    if (proj == 0) v *= QSCL;
                    dst[(((size_t)(b_ * 16 + h_) * 2048 + s_) << 6) + hd] = (_Float16)v;
                } else if (MODE == 1) {
                    int h_ = row >> 6, hd = row & 63;
                    int b_ = col >> 11, s_ = col & 2047;
                    int sp = (s_ & ~63) | vperm(s_ & 63);
                    O1[(((size_t)(b_ * 16 + h_) * 64 + hd) << 11) + sp] = (_Float16)v;
                } else {
                    Of[(size_t)row * N + col] = v + bias[col];
                }
            }
        }
}

// ---------------------------------------------------------------- attention tile step
// EXACT round-1 verified step (54us kernel): S^T = K.Q^T via mfma(kf, qf);
// exps packed in-register -> PV A-operand; V from LDS (vperm-matched). No P LDS.
template <bool MASKED>
__device__ __forceinline__ void attn_step5(const half8 qf[2],
                                           const _Float16* __restrict__ Ks,
                                           const _Float16* __restrict__ Vs,
                                           int krow0, int qt, int quad, int c,
                                           float4v o[4], float& l) {
    float4v sT[4] = {};
    __builtin_amdgcn_s_setprio(1);
#pragma unroll
    for (int nt = 0; nt < 4; ++nt)
#pragma unroll
        for (int ks = 0; ks < 2; ++ks) {
            half8 kf = *(const half8*)((const char*)Ks + swz(nt * 16 + c, ks * 64 + quad * 16));
            sT[nt] = __builtin_amdgcn_mfma_f32_16x16x32_f16(kf, qf[ks], sT[nt], 0, 0, 0);
        }
    __builtin_amdgcn_s_setprio(0);

    const int qrow_g = qt + c;
#pragma unroll
    for (int kk = 0; kk < 2; ++kk) {
        float e[2][4];
#pragma unroll
        for (int jh = 0; jh < 2; ++jh) {
            const int nt = 2 * kk + jh;
#pragma unroll
            for (int i = 0; i < 4; ++i) {
                float ev = __builtin_amdgcn_exp2f(sT[nt][i]);
                if (MASKED)
                    ev = (krow0 + nt * 16 + quad * 4 + i <= qrow_g) ? ev : 0.0f;
                e[jh][i] = ev;
                l += ev;
            }
        }
        auto p0 = __builtin_amdgcn_cvt_pkrtz(e[0][0], e[0][1]);
        auto p1 = __builtin_amdgcn_cvt_pkrtz(e[0][2], e[0][3]);
        auto p2 = __builtin_amdgcn_cvt_pkrtz(e[1][0], e[1][1]);
        auto p3 = __builtin_amdgcn_cvt_pkrtz(e[1][2], e[1][3]);
        half8 pf;
        pf[0] = p0[0]; pf[1] = p0[1]; pf[2] = p1[0]; pf[3] = p1[1];
        pf[4] = p2[0]; pf[5] = p2[1]; pf[6] = p3[0]; pf[7] = p3[1];
        __builtin_amdgcn_s_setprio(1);
#pragma unroll
        for (int dt = 0; dt < 4; ++dt) {
            half8 vf = *(const half8*)((const char*)Vs + swz(dt * 16 + c, kk * 64 + quad * 16));
            o[dt] = __builtin_amdgcn_mfma_f32_16x16x32_f16(pf, vf, o[dt], 0, 0, 0);
        }
        __builtin_amdgcn_s_setprio(0);
    }
}

// ---------------------------------------------------------------- flash attention
// flash5 inner code, one 64-row q-strip per block (occupancy lever):
// grid (16 h, 32 strips, 4 b) = 2048 blocks; LDS 32 KB -> 5 resident/CU =
// 20 waves/CU (flash5 was grid-capped at 4 blocks/CU, occupancy 29%, all
// pipes <45% = latency-bound). Work total identical; staging traffic doubles
// (measured irrelevant, R3/R4). Longest strips dispatch first (strip = 31-y).
// Tile kb == strip is the masked diagonal; kb < strip full.
__global__ __launch_bounds__(256, 4) void attn_flash11(const _Float16* __restrict__ Q,
                                                       const _Float16* __restrict__ Kg,
                                                       const _Float16* __restrict__ Vt,
                                                       _Float16* __restrict__ Ctx) {
    __shared__ __align__(16) _Float16 Ks[2 * 64 * 64];  // 16 KB dbuf
    __shared__ __align__(16) _Float16 Vs[2 * 64 * 64];  // 16 KB dbuf

    const int tid  = threadIdx.x;
    const int wave = tid >> 6;
    const int lane = tid & 63;
    const int quad = lane >> 4;
    const int c    = lane & 15;

    const int h     = blockIdx.x;
    const int strip = 31 - blockIdx.y;     // 64-row q-strip; longest first
    const int bb    = blockIdx.z;

    const int qt  = strip * 64 + wave * 16;   // this wave's 16 q-rows
    const int nkb = strip + 1;                // k-tiles incl. diagonal

    const _Float16* Qb  = Q  + ((size_t)(bb * 16 + h) << 17);
    const _Float16* Kb  = Kg + ((size_t)(bb * 16 + h) << 17);
    const _Float16* Vtb = Vt + ((size_t)(bb * 16 + h) << 17);

    half8 qf[2];
    {
        const _Float16* qa = Qb + (size_t)(qt + c) * 64;
        qf[0] = *(const half8*)(qa + quad * 8);
        qf[1] = *(const half8*)(qa + 32 + quad * 8);
    }

    size_t koff[2], voff[2];
#pragma unroll
    for (int it = 0; it < 2; ++it) {
        int F = it * 4096 + tid * 16;
        int r = F >> 7;
        int blk = (tid & 7) ^ (r & 7);
        koff[it] = (size_t)r * 64 + blk * 8;
        voff[it] = (size_t)r * 2048 + blk * 8;
    }

    float4v o[4] = {};
    float l = 0.0f;

    auto stage = [&](int kb, int buf) {
        const size_t kbase = (size_t)kb * 64 * 64;
#pragma unroll
        for (int it = 0; it < 2; ++it) {
            __builtin_amdgcn_global_load_lds(
                (const AS1 void*)(Kb + kbase + koff[it]),
                (AS3 void*)((char*)Ks + buf * 8192 + it * 4096 + wave * 1024), 16, 0, 0);
            __builtin_amdgcn_global_load_lds(
                (const AS1 void*)(Vtb + kb * 64 + voff[it]),
                (AS3 void*)((char*)Vs + buf * 8192 + it * 4096 + wave * 1024), 16, 0, 0);
        }
    };

    stage(0, 0);
    for (int kb = 0; kb < nkb; ++kb) {
        __syncthreads();                       // buf kb ready; prev buf free
        if (kb + 1 < nkb) stage(kb + 1, (kb + 1) & 1);

        const _Float16* Ksb = Ks + (kb & 1) * 4096;
        const _Float16* Vsb = Vs + (kb & 1) * 4096;
        const int krow0 = kb * 64;

        if (kb == strip)
            attn_step5<true >(qf, Ksb, Vsb, krow0, qt, quad, c, o, l);
        else
            attn_step5<false>(qf, Ksb, Vsb, krow0, qt, quad, c, o, l);
    }

    // ---- l reduction across quads (lanes with same c hold same qrow)
    l += __shfl_xor(l, 16); l += __shfl_xor(l, 32);

    // ---- normalize + write ctx [b, s, h*64+hd]
#pragma unroll
    for (int i = 0; i < 4; ++i) {
        const float inv = 1.0f / __shfl(l, quad * 4 + i);
        const int row_g = qt + quad * 4 + i;
        _Float16* dst = Ctx + (size_t)(bb * 2048 + row_g) * 1024 + h * 64;
#pragma unroll
        for (int dt = 0; dt < 4; ++dt)
            dst[dt * 16 + c] = (_Float16)(o[dt][i] * inv);
    }
}

// ---------------------------------------------------------------- launch
extern "C" void kernel_launch(void* const* d_in, const int* in_sizes, int n_in,
                              void* d_out, int out_size, void* d_ws, size_t ws_size,
                              hipStream_t stream) {
    const float* x  = (const float*)d_in[0];
    const float* Wq = (const float*)d_in[1];
    const float* Wk = (const float*)d_in[2];
    const float* Wv = (const float*)d_in[3];
    const float* Wo = (const float*)d_in[4];
    const float* bo = (const float*)d_in[5];
    float* out = (float*)d_out;

    _Float16* Xh   = (_Float16*)d_ws;
    _Float16* Wqkh = Xh + (size_t)M_ROWS * D_MODEL;      // Wq | Wk
    _Float16* Wvh  = Wqkh + (size_t)2 * D_MODEL * D_MODEL;
    _Float16* Woh  = Wvh + (size_t)D_MODEL * D_MODEL;
    _Float16* Qh   = Woh + (size_t)D_MODEL * D_MODEL;    // [b,h,s,hd], pre-scaled
    _Float16* Kh   = Qh + (size_t)M_ROWS * D_MODEL;      // [b,h,s,hd]
    _Float16* Vth  = Kh + (size_t)M_ROWS * D_MODEL;      // [b,h,hd,s'] vperm order
    _Float16* Ch   = Vth + (size_t)M_ROWS * D_MODEL;     // [b*s, d]

    static bool s_init = false;
    if (!s_init) {
        hipFuncSetAttribute((const void*)gemm8p<0>,
                            hipFuncAttributeMaxDynamicSharedMemorySize, GEMM_LDS);
        hipFuncSetAttribute((const void*)gemm8p<1>,
                            hipFuncAttributeMaxDynamicSharedMemorySize, GEMM_LDS);
        hipFuncSetAttribute((const void*)gemm8p<2>,
                            hipFuncAttributeMaxDynamicSharedMemorySize, GEMM_LDS);
        s_init = true;
    }

    const int TOT4 = (M_ROWS * D_MODEL + 4 * D_MODEL * D_MODEL) / 4;
    cvt_all<<<TOT4 / 256, 256, 0, stream>>>(x, Wq, Wk, Wv, Wo, Xh);

    gemm8p<0><<<dim3(M_ROWS / 256, 2048 / 128), 512, GEMM_LDS, stream>>>(
        Xh, Wqkh, Qh, Kh, nullptr, nullptr, 2048);
    gemm8p<1><<<dim3(D_MODEL / 256, M_ROWS / 128), 512, GEMM_LDS, stream>>>(
        Wvh, Xh, Vth, nullptr, nullptr, nullptr, M_ROWS);

    attn_flash11<<<dim3(N_HEADS, 32, BATCH), 256, 0, stream>>>(Qh, Kh, Vth, Ch);

    gemm8p<2><<<dim3(M_ROWS / 256, D_MODEL / 128), 512, GEMM_LDS, stream>>>(
        Ch, Woh, nullptr, nullptr, out, bo, D_MODEL);
}